// Round 5
// baseline (364.197 us; speedup 1.0000x reference)
//
#include <hip/hip_runtime.h>
#include <hip/hip_bf16.h>
#include <stdint.h>

// Problem dims (fixed by reference setup_inputs)
#define B_SZ 128
#define R_SZ 36       // real regions per image
#define RP_SZ 48      // padded regions (dup row 35) -> multiple of 16
#define W_SZ 60       // real words per caption
#define WP_SZ 64      // padded words (dup word 59, masked in epilogue)
#define D_SZ 1024
#define MARGIN 0.2f

#define ATILE (192 * 64)   // bf16 elems per A K-tile
#define BTILE (256 * 64)   // bf16 elems per B K-tile

typedef __attribute__((ext_vector_type(8))) short short8;   // 8 bf16 (MFMA A/B frag)
typedef __attribute__((ext_vector_type(4))) float f32x4;    // MFMA C/D frag

typedef __attribute__((address_space(3))) unsigned int lds_u32;
typedef const __attribute__((address_space(1))) unsigned int glb_u32;

__device__ __forceinline__ void gload16(const unsigned short* g, unsigned short* l) {
    __builtin_amdgcn_global_load_lds((glb_u32*)g, (lds_u32*)l, 16, 0, 0);
}

__device__ __forceinline__ unsigned short f2bf(float f) {
    union { float f; uint32_t u; } x; x.f = f;
    uint32_t u = x.u;
    uint32_t r = (u + 0x7FFFu + ((u >> 16) & 1u)) >> 16;   // RNE bf16
    return (unsigned short)r;
}

// Fused fp32 -> bf16 convert + row-pad for BOTH tensors in one launch.
__global__ __launch_bounds__(256) void convert_pad_kernel(
        const float* __restrict__ im, const float* __restrict__ s,
        unsigned short* __restrict__ imb, unsigned short* __restrict__ sb) {
    const int n4_im = B_SZ * RP_SZ * D_SZ / 4;
    const int n4_s  = B_SZ * WP_SZ * D_SZ / 4;
    int i = blockIdx.x * 256 + threadIdx.x;
    const float* src;
    unsigned short* dst;
    int srcIdx;
    if (i < n4_im) {
        int idx = i * 4;
        int d  = idx & (D_SZ - 1);
        int rj = idx >> 10;
        int r  = rj % RP_SZ;
        int j  = rj / RP_SZ;
        int rs = r < R_SZ ? r : R_SZ - 1;
        src = im; dst = imb + idx;
        srcIdx = ((j * R_SZ + rs) << 10) + d;
    } else {
        int i2 = i - n4_im;
        if (i2 >= n4_s) return;
        int idx = i2 * 4;
        int d  = idx & (D_SZ - 1);
        int rj = idx >> 10;
        int r  = rj & (WP_SZ - 1);
        int j  = rj >> 6;
        int rs = r < W_SZ ? r : W_SZ - 1;
        src = s; dst = sb + idx;
        srcIdx = ((j * W_SZ + rs) << 10) + d;
    }
    const float4 v = *reinterpret_cast<const float4*>(src + srcIdx);
    ushort4 o;
    o.x = f2bf(v.x); o.y = f2bf(v.y); o.z = f2bf(v.z); o.w = f2bf(v.w);
    *reinterpret_cast<ushort4*>(dst) = o;
}

// Fused GEMM + MISA epilogue — cross-tile register pipeline:
// Block 192x256, BK=64, 4 waves (2Mx2N), per-wave 96x128 (acc[6][8]), 1 wave/SIMD
// (512-VGPR budget). Per tile: wait slice0 (lgkmcnt(14)) -> MFMA slice0 ->
// lgkmcnt(0) -> vmcnt(0)+barrier -> stage kt+2 -> issue ALL of tile kt+1's 28
// ds_reads (ping-pong reg set) -> sched_barrier -> MFMA slice1. LDS serves
// kt+1's reads UNDER kt's MFMA1 and kt+1's MFMA0 — read/MFMA overlap, unlike
// the round-4 alternating phases. XOR slot-swizzle as validated (0 conflicts).
__global__ __launch_bounds__(256, 1) void scores_kernel(
        const unsigned short* __restrict__ imb,   // [128][48][1024] bf16 (padded)
        const unsigned short* __restrict__ sb,    // [128][64][1024] bf16 (padded)
        const int* __restrict__ s_l,
        float* __restrict__ S)                    // [j][i]
{
    __shared__ unsigned short As[2 * ATILE];
    __shared__ unsigned short Bs[2 * BTILE];

    const int tid  = threadIdx.x;
    const int wid  = tid >> 6;        // 0..3
    const int lane = tid & 63;
    const int l15  = lane & 15;
    const int kgrp = lane >> 4;       // 0..3
    const int wr   = wid >> 1;        // 0..1 (M)
    const int wc   = wid & 1;         // 0..1 (N)

    // XCD-chunked swizzle over 1024 blocks
    int bid = blockIdx.x;
    int swz = (bid & 7) * 128 + (bid >> 3);
    int jt = swz & 31;                // 0..31 (4 images each)
    int it = swz >> 5;                // 0..31 (4 captions each)

    // staging: 8 lanes per 128B row-segment, pre-swizzled source slot
    const int lrow = lane >> 3;                   // 0..7 == row&7 of staged row
    const int slot = (lane & 7) ^ lrow;           // LDS[row][s] = G[row][s^(row&7)]

    // A: 24 chunks (1 KB each), 6 per wave; B: 32 chunks, 8 per wave
    const unsigned short* gA[6];
    int aoff[6];
#pragma unroll
    for (int c = 0; c < 6; ++c) {
        int chunk = wid + c * 4;                  // 0..23
        int row = chunk * 8 + lrow;               // 0..191
        gA[c] = imb + (size_t)(jt * 192 + row) * D_SZ + slot * 8;
        aoff[c] = chunk * 512 + lane * 8;
    }
    const unsigned short* gB[8];
    int boff[8];
#pragma unroll
    for (int c = 0; c < 8; ++c) {
        int chunk = wid + c * 4;                  // 0..31
        int row = chunk * 8 + lrow;               // 0..255
        gB[c] = sb + (size_t)(it * 256 + row) * D_SZ + slot * 8;
        boff[c] = chunk * 512 + lane * 8;
    }

    // ds_read addressing: addr = row*64 + slot*8, slot = (k2*4+kgrp)^rsw
    // slice1 = slice0 ^ 32 (element offset)
    const int rsw = l15 & 7;
    const int k0off = (kgrp ^ rsw) * 8;
    int abase[6];
#pragma unroll
    for (int rf = 0; rf < 6; ++rf)
        abase[rf] = (wr * 96 + rf * 16 + l15) * 64 + k0off;
    int bbase[8];
#pragma unroll
    for (int cf = 0; cf < 8; ++cf)
        bbase[cf] = (wc * 128 + cf * 16 + l15) * 64 + k0off;

    f32x4 acc[6][8] = {};
    short8 a[2][2][6], b[2][2][8];   // [tile parity][k2 slice][frag]

    // prologue: stage tiles 0 and 1
#pragma unroll
    for (int c = 0; c < 6; ++c) gload16(gA[c], As + aoff[c]);
#pragma unroll
    for (int c = 0; c < 8; ++c) gload16(gB[c], Bs + boff[c]);
#pragma unroll
    for (int c = 0; c < 6; ++c) gload16(gA[c] + 64, As + ATILE + aoff[c]);
#pragma unroll
    for (int c = 0; c < 8; ++c) gload16(gB[c] + 64, Bs + BTILE + boff[c]);
    asm volatile("s_waitcnt vmcnt(14)" ::: "memory");   // tile 0 landed
    __builtin_amdgcn_s_barrier();

    // issue tile-0 reads (both slices) into parity-0 set
#pragma unroll
    for (int rf = 0; rf < 6; ++rf)
        a[0][0][rf] = *reinterpret_cast<const short8*>(As + abase[rf]);
#pragma unroll
    for (int cf = 0; cf < 8; ++cf)
        b[0][0][cf] = *reinterpret_cast<const short8*>(Bs + bbase[cf]);
#pragma unroll
    for (int rf = 0; rf < 6; ++rf)
        a[0][1][rf] = *reinterpret_cast<const short8*>(As + (abase[rf] ^ 32));
#pragma unroll
    for (int cf = 0; cf < 8; ++cf)
        b[0][1][cf] = *reinterpret_cast<const short8*>(Bs + (bbase[cf] ^ 32));

#pragma unroll 2
    for (int kt = 0; kt < 16; ++kt) {
        const int p = kt & 1;          // constant after unroll-2
        const int q = p ^ 1;
        const unsigned short* Aq = As + q * ATILE;
        const unsigned short* Bq = Bs + q * BTILE;

        asm volatile("s_waitcnt lgkmcnt(14)" ::: "memory");   // slice0 landed
        __builtin_amdgcn_s_setprio(1);
#pragma unroll
        for (int rf = 0; rf < 6; ++rf)
#pragma unroll
            for (int cf = 0; cf < 8; ++cf)
                acc[rf][cf] = __builtin_amdgcn_mfma_f32_16x16x32_bf16(
                    a[p][0][rf], b[p][0][cf], acc[rf][cf], 0, 0, 0);
        __builtin_amdgcn_s_setprio(0);
        asm volatile("s_waitcnt lgkmcnt(0)" ::: "memory");    // slice1 landed

        if (kt < 15) {
            asm volatile("s_waitcnt vmcnt(0)" ::: "memory");  // tile kt+1 staged
            __builtin_amdgcn_s_barrier();   // all waves done reading buf[p]
            if (kt < 14) {                  // stage kt+2 into buf[p] (now dead)
                const int ko = (kt + 2) * 64;
                unsigned short* Ad = As + p * ATILE;
                unsigned short* Bd = Bs + p * BTILE;
#pragma unroll
                for (int c = 0; c < 6; ++c) gload16(gA[c] + ko, Ad + aoff[c]);
#pragma unroll
                for (int c = 0; c < 8; ++c) gload16(gB[c] + ko, Bd + boff[c]);
            }
            // issue ALL of tile kt+1's reads now -> served under MFMA1(kt)+MFMA0(kt+1)
#pragma unroll
            for (int rf = 0; rf < 6; ++rf)
                a[q][0][rf] = *reinterpret_cast<const short8*>(Aq + abase[rf]);
#pragma unroll
            for (int cf = 0; cf < 8; ++cf)
                b[q][0][cf] = *reinterpret_cast<const short8*>(Bq + bbase[cf]);
#pragma unroll
            for (int rf = 0; rf < 6; ++rf)
                a[q][1][rf] = *reinterpret_cast<const short8*>(Aq + (abase[rf] ^ 32));
#pragma unroll
            for (int cf = 0; cf < 8; ++cf)
                b[q][1][cf] = *reinterpret_cast<const short8*>(Bq + (bbase[cf] ^ 32));
            __builtin_amdgcn_sched_barrier(0);   // pin read-issue before MFMA1
        }

        __builtin_amdgcn_s_setprio(1);
#pragma unroll
        for (int rf = 0; rf < 6; ++rf)
#pragma unroll
            for (int cf = 0; cf < 8; ++cf)
                acc[rf][cf] = __builtin_amdgcn_mfma_f32_16x16x32_bf16(
                    a[p][1][rf], b[p][1][cf], acc[rf][cf], 0, 0, 0);
        __builtin_amdgcn_s_setprio(0);
    }

    // Epilogue: wave (wr,wc) owns images j = jt*4 + wr*2 + {0,1} (rf trios)
    // and captions i = it*4 + wc*2 + {0,1} (cf quads).
    // C frag layout: col = l15 (word), row = kgrp*4 + e (region).
#pragma unroll
    for (int c = 0; c < 2; ++c) {
        const int i_cap = it * 4 + wc * 2 + c;
        const int nw = s_l[i_cap];
        const float inv = 1.0f / (float)nw;
#pragma unroll
        for (int h = 0; h < 2; ++h) {
            float sum = 0.0f;
#pragma unroll
            for (int cfl = 0; cfl < 4; ++cfl) {
                const int cf = c * 4 + cfl;
                float m = acc[h * 3][cf][0];
#pragma unroll
                for (int rf = h * 3; rf < h * 3 + 3; ++rf)
#pragma unroll
                    for (int e = 0; e < 4; ++e)
                        m = fmaxf(m, acc[rf][cf][e]);
                m = fmaxf(m, __shfl_xor(m, 16));
                m = fmaxf(m, __shfl_xor(m, 32));
                int wv = cfl * 16 + l15;
                if (wv < nw) sum += m;
            }
            sum += __shfl_xor(sum, 1);
            sum += __shfl_xor(sum, 2);
            sum += __shfl_xor(sum, 4);
            sum += __shfl_xor(sum, 8);
            if (lane == 0) {
                int j_img = jt * 4 + wr * 2 + h;
                S[j_img * B_SZ + i_cap] = sum * inv;
            }
        }
    }
}

// Contrastive loss over the 128x128 score matrix, single block
__global__ __launch_bounds__(256) void loss_kernel(
        const float* __restrict__ S, float* __restrict__ out) {
    __shared__ float diag[B_SZ];
    __shared__ float red[256];
    int t = threadIdx.x;
    if (t < B_SZ) diag[t] = S[t * (B_SZ + 1)];
    __syncthreads();
    float acc = 0.0f;
    for (int idx = t; idx < B_SZ * B_SZ; idx += 256) {
        int a = idx >> 7, b = idx & (B_SZ - 1);
        if (a != b) {
            float v = S[idx];
            acc += fmaxf(MARGIN + v - diag[a], 0.0f)
                 + fmaxf(MARGIN + v - diag[b], 0.0f);
        }
    }
    red[t] = acc;
    __syncthreads();
    for (int s = 128; s > 0; s >>= 1) {
        if (t < s) red[t] += red[t + s];
        __syncthreads();
    }
    if (t == 0) out[0] = red[0];
}

extern "C" void kernel_launch(void* const* d_in, const int* in_sizes, int n_in,
                              void* d_out, int out_size, void* d_ws, size_t ws_size,
                              hipStream_t stream) {
    const float* im  = (const float*)d_in[0];
    const float* s   = (const float*)d_in[1];
    const int*   s_l = (const int*)d_in[2];
    // d_in[3] (x) unused by the math

    const int n_im_pad = B_SZ * RP_SZ * D_SZ;   // 6,291,456
    const int n_s_pad  = B_SZ * WP_SZ * D_SZ;   // 8,388,608

    unsigned short* imb = (unsigned short*)d_ws;
    unsigned short* sb  = imb + n_im_pad;
    float* S = (float*)(sb + n_s_pad);          // 128*128 floats

    const int n4_total = (n_im_pad + n_s_pad) / 4;
    convert_pad_kernel<<<(n4_total + 255) / 256, 256, 0, stream>>>(im, s, imb, sb);

    scores_kernel<<<1024, 256, 0, stream>>>(imb, sb, s_l, S);

    loss_kernel<<<1, 256, 0, stream>>>(S, (float*)d_out);
}

// Round 6
// 171.405 us; speedup vs baseline: 2.1248x; 2.1248x over previous
//
#include <hip/hip_runtime.h>
#include <hip/hip_bf16.h>
#include <stdint.h>

// Problem dims (fixed by reference setup_inputs)
#define B_SZ 128
#define R_SZ 36       // real regions per image
#define RP_SZ 48      // padded regions (dup row 35) -> multiple of 16
#define W_SZ 60       // real words per caption
#define WP_SZ 64      // padded words (dup word 59, masked in epilogue)
#define D_SZ 1024
#define MARGIN 0.2f

#define ATILE (192 * 64)   // bf16 elems per A K-tile
#define BTILE (256 * 64)   // bf16 elems per B K-tile

typedef __attribute__((ext_vector_type(8))) short short8;     // 8 bf16 (MFMA A/B frag)
typedef __attribute__((ext_vector_type(16))) float f32x16;    // 32x32 MFMA C/D frag

typedef __attribute__((address_space(3))) unsigned int lds_u32;
typedef const __attribute__((address_space(1))) unsigned int glb_u32;

__device__ __forceinline__ void gload16(const unsigned short* g, unsigned short* l) {
    __builtin_amdgcn_global_load_lds((glb_u32*)g, (lds_u32*)l, 16, 0, 0);
}

__device__ __forceinline__ unsigned short f2bf(float f) {
    union { float f; uint32_t u; } x; x.f = f;
    uint32_t u = x.u;
    uint32_t r = (u + 0x7FFFu + ((u >> 16) & 1u)) >> 16;   // RNE bf16
    return (unsigned short)r;
}

// Fused fp32 -> bf16 convert + row-pad for BOTH tensors in one launch.
__global__ __launch_bounds__(256) void convert_pad_kernel(
        const float* __restrict__ im, const float* __restrict__ s,
        unsigned short* __restrict__ imb, unsigned short* __restrict__ sb) {
    const int n4_im = B_SZ * RP_SZ * D_SZ / 4;
    const int n4_s  = B_SZ * WP_SZ * D_SZ / 4;
    int i = blockIdx.x * 256 + threadIdx.x;
    const float* src;
    unsigned short* dst;
    int srcIdx;
    if (i < n4_im) {
        int idx = i * 4;
        int d  = idx & (D_SZ - 1);
        int rj = idx >> 10;
        int r  = rj % RP_SZ;
        int j  = rj / RP_SZ;
        int rs = r < R_SZ ? r : R_SZ - 1;
        src = im; dst = imb + idx;
        srcIdx = ((j * R_SZ + rs) << 10) + d;
    } else {
        int i2 = i - n4_im;
        if (i2 >= n4_s) return;
        int idx = i2 * 4;
        int d  = idx & (D_SZ - 1);
        int rj = idx >> 10;
        int r  = rj & (WP_SZ - 1);
        int j  = rj >> 6;
        int rs = r < W_SZ ? r : W_SZ - 1;
        src = s; dst = sb + idx;
        srcIdx = ((j * W_SZ + rs) << 10) + d;
    }
    const float4 v = *reinterpret_cast<const float4*>(src + srcIdx);
    ushort4 o;
    o.x = f2bf(v.x); o.y = f2bf(v.y); o.z = f2bf(v.z); o.w = f2bf(v.w);
    *reinterpret_cast<ushort4*>(dst) = o;
}

// Fused GEMM + MISA epilogue, 32x32x16 MFMA, compiler-interleaved window:
// Block 192x256, BK=64, 4 waves (2Mx2N), per-wave 96x128 = acc[3][4] f32x16
// (192 regs -> AGPR side of unified file; frag working set 7x short8 only).
// Per K-tile ONE window: 28 ds_read_b128 issued, MFMAs follow with
// compiler-emitted counted lgkmcnt (NO explicit lgkmcnt(0) -> slice-k MFMAs
// overlap slice-k+1 reads). One vmcnt(0)+s_barrier per tile; staging of
// kt+2 issued right after the barrier (full-tile flight time).
// XOR slot-swizzle validated in rounds 2-4 (0 bank conflicts).
__global__ __launch_bounds__(256, 1) void scores_kernel(
        const unsigned short* __restrict__ imb,   // [128][48][1024] bf16 (padded)
        const unsigned short* __restrict__ sb,    // [128][64][1024] bf16 (padded)
        const int* __restrict__ s_l,
        float* __restrict__ S)                    // [j][i]
{
    __shared__ unsigned short As[2 * ATILE];
    __shared__ unsigned short Bs[2 * BTILE];

    const int tid  = threadIdx.x;
    const int wid  = tid >> 6;        // 0..3
    const int lane = tid & 63;
    const int l31  = lane & 31;
    const int hi   = lane >> 5;       // 0..1
    const int l7   = lane & 7;
    const int wr   = wid >> 1;        // 0..1 (M)
    const int wc   = wid & 1;         // 0..1 (N)

    // XCD-chunked swizzle over 1024 blocks
    int bid = blockIdx.x;
    int swz = (bid & 7) * 128 + (bid >> 3);
    int jt = swz & 31;                // 0..31 (4 images each)
    int it = swz >> 5;                // 0..31 (4 captions each)

    // staging: 8 lanes per 128B row-segment, pre-swizzled source slot
    const int lrow = lane >> 3;                   // 0..7 == row&7 of staged row
    const int slot = (lane & 7) ^ lrow;           // LDS[row][s] = G[row][s^(row&7)]

    // A: 24 chunks (8 rows x 64 K each), 6 per wave; B: 32 chunks, 8 per wave
    const unsigned short* gA[6];
    int aoff[6];
#pragma unroll
    for (int c = 0; c < 6; ++c) {
        int chunk = wid + c * 4;                  // 0..23
        int row = chunk * 8 + lrow;               // 0..191
        gA[c] = imb + (size_t)(jt * 192 + row) * D_SZ + slot * 8;
        aoff[c] = chunk * 512 + lane * 8;         // linear: base + lane*16B
    }
    const unsigned short* gB[8];
    int boff[8];
#pragma unroll
    for (int c = 0; c < 8; ++c) {
        int chunk = wid + c * 4;                  // 0..31
        int row = chunk * 8 + lrow;               // 0..255
        gB[c] = sb + (size_t)(it * 256 + row) * D_SZ + slot * 8;
        boff[c] = chunk * 512 + lane * 8;
    }

    // ds_read addressing: elem = row*64 + ((ks*2+hi) ^ (row&7))*8 ; row&7 == l7
    int arow[3];
#pragma unroll
    for (int rf = 0; rf < 3; ++rf)
        arow[rf] = (wr * 96 + rf * 32 + l31) * 64;
    int brow[4];
#pragma unroll
    for (int cf = 0; cf < 4; ++cf)
        brow[cf] = (wc * 128 + cf * 32 + l31) * 64;

    f32x16 acc[3][4] = {};

    // prologue: stage tiles 0 and 1
#pragma unroll
    for (int c = 0; c < 6; ++c) gload16(gA[c], As + aoff[c]);
#pragma unroll
    for (int c = 0; c < 8; ++c) gload16(gB[c], Bs + boff[c]);
#pragma unroll
    for (int c = 0; c < 6; ++c) gload16(gA[c] + 64, As + ATILE + aoff[c]);
#pragma unroll
    for (int c = 0; c < 8; ++c) gload16(gB[c] + 64, Bs + BTILE + boff[c]);
    asm volatile("s_waitcnt vmcnt(14)" ::: "memory");   // tile 0 landed
    __builtin_amdgcn_s_barrier();

#pragma unroll 2
    for (int kt = 0; kt < 16; ++kt) {
        const int cur = kt & 1;
        const unsigned short* Ac = As + cur * ATILE;
        const unsigned short* Bc = Bs + cur * BTILE;

        short8 af[4][3], bf[4][4];
#pragma unroll
        for (int ks = 0; ks < 4; ++ks) {
            const int sl8 = (((ks * 2 + hi) ^ l7) * 8);
#pragma unroll
            for (int rf = 0; rf < 3; ++rf)
                af[ks][rf] = *reinterpret_cast<const short8*>(Ac + arow[rf] + sl8);
#pragma unroll
            for (int cf = 0; cf < 4; ++cf)
                bf[ks][cf] = *reinterpret_cast<const short8*>(Bc + brow[cf] + sl8);
        }
        // MFMAs: compiler inserts counted lgkmcnt per frag dependency ->
        // early ksteps compute while later ksteps' reads are still in flight.
#pragma unroll
        for (int ks = 0; ks < 4; ++ks)
#pragma unroll
            for (int rf = 0; rf < 3; ++rf)
#pragma unroll
                for (int cf = 0; cf < 4; ++cf)
                    acc[rf][cf] = __builtin_amdgcn_mfma_f32_32x32x16_bf16(
                        af[ks][rf], bf[ks][cf], acc[rf][cf], 0, 0, 0);

        if (kt < 15) {
            asm volatile("s_waitcnt vmcnt(0)" ::: "memory");  // tile kt+1 staged
            __builtin_amdgcn_s_barrier();   // all waves done reading buf[cur]
            if (kt < 14) {                  // stage kt+2 into buf[cur] (now dead)
                const int ko = (kt + 2) * 64;
                unsigned short* Ad = As + cur * ATILE;
                unsigned short* Bd = Bs + cur * BTILE;
#pragma unroll
                for (int c = 0; c < 6; ++c) gload16(gA[c] + ko, Ad + aoff[c]);
#pragma unroll
                for (int c = 0; c < 8; ++c) gload16(gB[c] + ko, Bd + boff[c]);
            }
        }
    }

    // Epilogue. 32x32 C/D layout: col = lane&31, local row = (reg&3)+8*(reg>>2)+4*hi.
    // Wave rows = wr*96 + rf*32 + local -> image h rows [48h,48h+48):
    //   img0 = rf0 regs 0..15 + rf1 regs 0..7; img1 = rf1 regs 8..15 + rf2 regs 0..15.
    // Wave cols = wc*128 + cf*32 + col -> caption c (cf = 2c+cfl), word w = cfl*32+col.
#pragma unroll
    for (int c = 0; c < 2; ++c) {
        const int i_cap = it * 4 + wc * 2 + c;
        const int nw = s_l[i_cap];
        const float inv = 1.0f / (float)nw;
#pragma unroll
        for (int h = 0; h < 2; ++h) {
            float sum = 0.0f;
#pragma unroll
            for (int cfl = 0; cfl < 2; ++cfl) {
                const int cf = c * 2 + cfl;
                float m;
                if (h == 0) {
                    m = acc[0][cf][0];
#pragma unroll
                    for (int e = 1; e < 16; ++e) m = fmaxf(m, acc[0][cf][e]);
#pragma unroll
                    for (int e = 0; e < 8; ++e)  m = fmaxf(m, acc[1][cf][e]);
                } else {
                    m = acc[2][cf][0];
#pragma unroll
                    for (int e = 1; e < 16; ++e) m = fmaxf(m, acc[2][cf][e]);
#pragma unroll
                    for (int e = 8; e < 16; ++e) m = fmaxf(m, acc[1][cf][e]);
                }
                m = fmaxf(m, __shfl_xor(m, 32));   // combine hi/lo row halves
                int w = cfl * 32 + l31;
                if (w < nw) sum += m;
            }
            sum += __shfl_xor(sum, 1);
            sum += __shfl_xor(sum, 2);
            sum += __shfl_xor(sum, 4);
            sum += __shfl_xor(sum, 8);
            sum += __shfl_xor(sum, 16);
            if (lane == 0) {
                int j_img = jt * 4 + wr * 2 + h;
                S[j_img * B_SZ + i_cap] = sum * inv;
            }
        }
    }
}

// Contrastive loss over the 128x128 score matrix, single block
__global__ __launch_bounds__(256) void loss_kernel(
        const float* __restrict__ S, float* __restrict__ out) {
    __shared__ float diag[B_SZ];
    __shared__ float red[256];
    int t = threadIdx.x;
    if (t < B_SZ) diag[t] = S[t * (B_SZ + 1)];
    __syncthreads();
    float acc = 0.0f;
    for (int idx = t; idx < B_SZ * B_SZ; idx += 256) {
        int a = idx >> 7, b = idx & (B_SZ - 1);
        if (a != b) {
            float v = S[idx];
            acc += fmaxf(MARGIN + v - diag[a], 0.0f)
                 + fmaxf(MARGIN + v - diag[b], 0.0f);
        }
    }
    red[t] = acc;
    __syncthreads();
    for (int s = 128; s > 0; s >>= 1) {
        if (t < s) red[t] += red[t + s];
        __syncthreads();
    }
    if (t == 0) out[0] = red[0];
}

extern "C" void kernel_launch(void* const* d_in, const int* in_sizes, int n_in,
                              void* d_out, int out_size, void* d_ws, size_t ws_size,
                              hipStream_t stream) {
    const float* im  = (const float*)d_in[0];
    const float* s   = (const float*)d_in[1];
    const int*   s_l = (const int*)d_in[2];
    // d_in[3] (x) unused by the math

    const int n_im_pad = B_SZ * RP_SZ * D_SZ;   // 6,291,456
    const int n_s_pad  = B_SZ * WP_SZ * D_SZ;   // 8,388,608

    unsigned short* imb = (unsigned short*)d_ws;
    unsigned short* sb  = imb + n_im_pad;
    float* S = (float*)(sb + n_s_pad);          // 128*128 floats

    const int n4_total = (n_im_pad + n_s_pad) / 4;
    convert_pad_kernel<<<(n4_total + 255) / 256, 256, 0, stream>>>(im, s, imb, sb);

    scores_kernel<<<1024, 256, 0, stream>>>(imb, sb, s_l, S);

    loss_kernel<<<1, 256, 0, stream>>>(S, (float*)d_out);
}